// Round 10
// baseline (90.270 us; speedup 1.0000x reference)
//
#include <hip/hip_runtime.h>
#include <hip/hip_bf16.h>
#include <float.h>

// Problem constants (B, N, M from the reference)
#define B_      8
#define N_      8192
#define M_      8192
#define THREADS 256
#define P       8                    // a-points per thread: amortize each ds_read over 8 FMA chains
#define SPLIT   16                   // M-loop split factor
#define CHUNK   (M_ / SPLIT)         // 512 b-points per block
#define APB     (THREADS * P)        // 2048 a-points per block
#define ATILES  (N_ / APB)           // 4 a-tiles per (batch, dir)
#define NBLOCKS (2 * SPLIT * ATILES * B_)  // 1024 = 4 blocks/CU, 16 waves/CU

// Fused prologue: pack xyz [n,3] -> float4 (x,y,z,|p|^2) for BOTH inputs AND
// init out[i] = FLT_MAX (atomicMin target). n_total = B*(N+M) == out_size.
__global__ void prep_kernel(const float* __restrict__ xyz1,
                            const float* __restrict__ xyz2,
                            float4* __restrict__ pk,      // [B*N] then [B*M]
                            float* __restrict__ out, int n1, int n_total) {
    int i = blockIdx.x * blockDim.x + threadIdx.x;
    if (i < n_total) {
        const float* src = (i < n1) ? (xyz1 + 3 * i) : (xyz2 + 3 * (i - n1));
        float x = src[0], y = src[1], z = src[2];
        pk[i] = make_float4(x, y, z, fmaf(x, x, fmaf(y, y, z * z)));
        out[i] = FLT_MAX;
    }
}

__global__ void init_kernel(float* __restrict__ out, int n) {
    int i = blockIdx.x * blockDim.x + threadIdx.x;
    if (i < n) out[i] = FLT_MAX;
}

// Pure-LDS main kernel, P=8. R9 proved mixing s_load into the b-path is a
// loss (SMEM returns out-of-order -> lgkmcnt(0) drains the ds queue), so all
// b comes from LDS broadcast (uniform-address ds_read_b128, conflict-free).
// P=8 halves LDS-pipe pressure per FMA vs R8: per-CU ds_reads 16.4k -> 8.2k
// (~98k cyc), below the ~115k-cyc VALU issue floor -> VALU-bound.
// Live set kept ~44 regs (aw[] dropped, reloaded in epilogue) to stay in the
// allocator's clean-VGPR regime (AGPR shuffle tax seen R2/R6/R7 at bigger
// live sets: ~2x instr bloat).
__global__ __launch_bounds__(THREADS, 4) void chamfer_lds(
    const float4* __restrict__ pk1,   // packed xyz1 [B*N]
    const float4* __restrict__ pk2,   // packed xyz2 [B*M]
    float* __restrict__ out)          // [B*N] dist1 then [B*M] dist2
{
    __shared__ float4 sb[CHUNK];      // 8 KB

    int bid = blockIdx.x;
    int dir   = bid & 1;                 bid >>= 1;
    int chunk = bid & (SPLIT - 1);       bid /= SPLIT;
    int atile = bid & (ATILES - 1);      bid /= ATILES;
    int batch = bid;                                      // 0..B_-1

    const float4* Ap = dir ? pk2 : pk1;
    const float4* Bp = (dir ? pk1 : pk2) + batch * M_ + chunk * CHUNK;
    float* o = out + (dir ? (B_ * N_) : 0);

    // stage b-chunk into LDS (coalesced dwordx4, 2 per thread)
    for (int t = threadIdx.x; t < CHUNK; t += THREADS)
        sb[t] = Bp[t];

    const int a0 = batch * N_ + atile * APB + threadIdx.x;

    float ax2[P], ay2[P], az2[P], m[P];
#pragma unroll
    for (int p = 0; p < P; ++p) {
        float4 a = Ap[a0 + p * THREADS];   // coalesced dwordx4
        ax2[p] = -2.0f * a.x;
        ay2[p] = -2.0f * a.y;
        az2[p] = -2.0f * a.z;
        m[p]   = FLT_MAX;
    }

    __syncthreads();

#pragma unroll 2
    for (int j = 0; j < CHUNK; j += 2) {
        float4 b0 = sb[j];        // uniform addr -> ds_read_b128 broadcast
        float4 b1 = sb[j + 1];
#pragma unroll
        for (int p = 0; p < P; ++p) {
            float t0 = fmaf(az2[p], b0.z, b0.w);
            t0 = fmaf(ay2[p], b0.y, t0);
            t0 = fmaf(ax2[p], b0.x, t0);
            float t1 = fmaf(az2[p], b1.z, b1.w);
            t1 = fmaf(ay2[p], b1.y, t1);
            t1 = fmaf(ax2[p], b1.x, t1);
            // m = min(m, t0, t1); inputs finite -> NaN semantics moot.
            // asm pins m[p] to an arch VGPR (R8's clean-allocation recipe).
            asm("v_min3_f32 %0, %0, %1, %2"
                : "+v"(m[p]) : "v"(t0), "v"(t1));
        }
    }

#pragma unroll
    for (int p = 0; p < P; ++p) {
        float4 a = Ap[a0 + p * THREADS];         // reload just for a.w (L2-hot)
        float d = fmaxf(a.w + m[p], 0.0f);       // clamp keeps uint-min valid
        atomicMin((unsigned int*)(o + a0 + p * THREADS), __float_as_uint(d));
    }
}

// Fallback if ws too small: raw reads, scalar math (known-good from R2).
#define FP      8
#define FSPLIT  8
#define FCHUNK  (M_ / FSPLIT)
#define FAPB    (THREADS * FP)
#define FATILES (N_ / FAPB)
#define FNBLOCKS (2 * FSPLIT * FATILES * B_)
__global__ __launch_bounds__(THREADS) void chamfer_raw(
    const float* __restrict__ xyz1,
    const float* __restrict__ xyz2,
    float* __restrict__ out)
{
    int bid = blockIdx.x;
    int dir   = bid & 1;                 bid >>= 1;
    int chunk = bid & (FSPLIT - 1);      bid /= FSPLIT;
    int atile = bid & (FATILES - 1);     bid /= FATILES;
    int batch = bid;

    const float* A  = dir ? xyz2 : xyz1;
    const float* Bp = dir ? xyz1 : xyz2;
    float* o = out + (dir ? (B_ * N_) : 0);

    const int a0 = batch * N_ + atile * FAPB + threadIdx.x;

    float ax2[FP], ay2[FP], az2[FP], aw[FP], m[FP];
#pragma unroll
    for (int p = 0; p < FP; ++p) {
        int idx = a0 + p * THREADS;
        float x = A[3 * idx + 0];
        float y = A[3 * idx + 1];
        float z = A[3 * idx + 2];
        ax2[p] = -2.0f * x;
        ay2[p] = -2.0f * y;
        az2[p] = -2.0f * z;
        aw[p]  = fmaf(x, x, fmaf(y, y, z * z));
        m[p]   = FLT_MAX;
    }

    const float* bp = Bp + 3 * (batch * M_ + chunk * FCHUNK);
#pragma unroll 2
    for (int j = 0; j < FCHUNK; j += 2) {
        float b0x = bp[3 * j + 0], b0y = bp[3 * j + 1], b0z = bp[3 * j + 2];
        float b1x = bp[3 * j + 3], b1y = bp[3 * j + 4], b1z = bp[3 * j + 5];
        float b0w = fmaf(b0x, b0x, fmaf(b0y, b0y, b0z * b0z));
        float b1w = fmaf(b1x, b1x, fmaf(b1y, b1y, b1z * b1z));
#pragma unroll
        for (int p = 0; p < FP; ++p) {
            float t0 = fmaf(ax2[p], b0x, b0w);
            t0 = fmaf(ay2[p], b0y, t0);
            t0 = fmaf(az2[p], b0z, t0);
            float t1 = fmaf(ax2[p], b1x, b1w);
            t1 = fmaf(ay2[p], b1y, t1);
            t1 = fmaf(az2[p], b1z, t1);
            m[p] = fminf(m[p], fminf(t0, t1));
        }
    }

#pragma unroll
    for (int p = 0; p < FP; ++p) {
        float d = fmaxf(aw[p] + m[p], 0.0f);
        atomicMin((unsigned int*)(o + a0 + p * THREADS), __float_as_uint(d));
    }
}

extern "C" void kernel_launch(void* const* d_in, const int* in_sizes, int n_in,
                              void* d_out, int out_size, void* d_ws, size_t ws_size,
                              hipStream_t stream) {
    const float* xyz1 = (const float*)d_in[0];
    const float* xyz2 = (const float*)d_in[1];
    float* out = (float*)d_out;

    const int n_out = B_ * N_ + B_ * M_;   // 131072

    const size_t need = (size_t)(B_ * (N_ + M_)) * sizeof(float4);  // 2 MiB
    if (ws_size >= need) {
        float4* pk1 = (float4*)d_ws;          // [B*N]; pk2 follows at [B*M]
        prep_kernel<<<(n_out + 255) / 256, 256, 0, stream>>>(
            xyz1, xyz2, pk1, out, B_ * N_, n_out);
        chamfer_lds<<<NBLOCKS, THREADS, 0, stream>>>(pk1, pk1 + (size_t)B_ * N_, out);
    } else {
        init_kernel<<<(n_out + 255) / 256, 256, 0, stream>>>(out, n_out);
        chamfer_raw<<<FNBLOCKS, THREADS, 0, stream>>>(xyz1, xyz2, out);
    }
}

// Round 11
// 88.720 us; speedup vs baseline: 1.0175x; 1.0175x over previous
//
#include <hip/hip_runtime.h>
#include <hip/hip_bf16.h>
#include <float.h>

// Problem constants (B, N, M from the reference)
#define B_      8
#define N_      8192
#define M_      8192
#define THREADS 256
#define P       8                    // a-points per thread: amortize each ds_read over 8 FMA chains
#define SPLIT   32                   // M-loop split factor (keeps 2048 blocks with P=8)
#define CHUNK   (M_ / SPLIT)         // 256 b-points per block (4 KB LDS)
#define APB     (THREADS * P)        // 2048 a-points per block
#define ATILES  (N_ / APB)           // 4 a-tiles per (batch, dir)
#define NBLOCKS (2 * SPLIT * ATILES * B_)  // 2048 = 8 blocks/CU, 32 waves/CU

// Fused prologue: pack xyz [n,3] -> float4 (x,y,z,|p|^2) for BOTH inputs AND
// init out[i] = FLT_MAX (atomicMin target). n_total = B*(N+M) == out_size.
__global__ void prep_kernel(const float* __restrict__ xyz1,
                            const float* __restrict__ xyz2,
                            float4* __restrict__ pk,      // [B*N] then [B*M]
                            float* __restrict__ out, int n1, int n_total) {
    int i = blockIdx.x * blockDim.x + threadIdx.x;
    if (i < n_total) {
        const float* src = (i < n1) ? (xyz1 + 3 * i) : (xyz2 + 3 * (i - n1));
        float x = src[0], y = src[1], z = src[2];
        pk[i] = make_float4(x, y, z, fmaf(x, x, fmaf(y, y, z * z)));
        out[i] = FLT_MAX;
    }
}

__global__ void init_kernel(float* __restrict__ out, int n) {
    int i = blockIdx.x * blockDim.x + threadIdx.x;
    if (i < n) out[i] = FLT_MAX;
}

// Pure-LDS main kernel, P=8 + SPLIT=32.
// Evidence so far:
//   R8  (P=4, 8 waves/SIMD): wall == LDS-pipe time (16.4k ds_read/CU x 12cyc)
//   R10 (P=8, 4 waves/SIMD): LDS pipe halved but latency exposed -> slower
// This round: P=8 halves LDS-pipe pressure AND SPLIT=32 restores 8 blocks/CU
// (32 waves/CU) so ds_read latency is hidden again. Expected bound: VALU
// issue (~114.7k cyc/SIMD = 47.8 us) with LDS pipe at 98k cyc underneath.
__global__ __launch_bounds__(THREADS, 4) void chamfer_lds(
    const float4* __restrict__ pk1,   // packed xyz1 [B*N]
    const float4* __restrict__ pk2,   // packed xyz2 [B*M]
    float* __restrict__ out)          // [B*N] dist1 then [B*M] dist2
{
    __shared__ float4 sb[CHUNK];      // 4 KB

    int bid = blockIdx.x;
    int dir   = bid & 1;                 bid >>= 1;
    int chunk = bid & (SPLIT - 1);       bid /= SPLIT;
    int atile = bid & (ATILES - 1);      bid /= ATILES;
    int batch = bid;                                      // 0..B_-1

    const float4* Ap = dir ? pk2 : pk1;
    const float4* Bp = (dir ? pk1 : pk2) + batch * M_ + chunk * CHUNK;
    float* o = out + (dir ? (B_ * N_) : 0);

    // stage b-chunk into LDS (coalesced dwordx4, 1 per thread)
    for (int t = threadIdx.x; t < CHUNK; t += THREADS)
        sb[t] = Bp[t];

    const int a0 = batch * N_ + atile * APB + threadIdx.x;

    float ax2[P], ay2[P], az2[P], m[P];
#pragma unroll
    for (int p = 0; p < P; ++p) {
        float4 a = Ap[a0 + p * THREADS];   // coalesced dwordx4
        ax2[p] = -2.0f * a.x;
        ay2[p] = -2.0f * a.y;
        az2[p] = -2.0f * a.z;
        m[p]   = FLT_MAX;
    }

    __syncthreads();

#pragma unroll 2
    for (int j = 0; j < CHUNK; j += 2) {
        float4 b0 = sb[j];        // uniform addr -> ds_read_b128 broadcast
        float4 b1 = sb[j + 1];
#pragma unroll
        for (int p = 0; p < P; ++p) {
            float t0 = fmaf(az2[p], b0.z, b0.w);
            t0 = fmaf(ay2[p], b0.y, t0);
            t0 = fmaf(ax2[p], b0.x, t0);
            float t1 = fmaf(az2[p], b1.z, b1.w);
            t1 = fmaf(ay2[p], b1.y, t1);
            t1 = fmaf(ax2[p], b1.x, t1);
            // m = min(m, t0, t1); inputs finite -> NaN semantics moot.
            // asm pins m[p] to an arch VGPR (clean-allocation recipe).
            asm("v_min3_f32 %0, %0, %1, %2"
                : "+v"(m[p]) : "v"(t0), "v"(t1));
        }
    }

#pragma unroll
    for (int p = 0; p < P; ++p) {
        float4 a = Ap[a0 + p * THREADS];         // reload just for a.w (L2-hot)
        float d = fmaxf(a.w + m[p], 0.0f);       // clamp keeps uint-min valid
        atomicMin((unsigned int*)(o + a0 + p * THREADS), __float_as_uint(d));
    }
}

// Fallback if ws too small: raw reads, scalar math (known-good from R2).
#define FP      8
#define FSPLIT  8
#define FCHUNK  (M_ / FSPLIT)
#define FAPB    (THREADS * FP)
#define FATILES (N_ / FAPB)
#define FNBLOCKS (2 * FSPLIT * FATILES * B_)
__global__ __launch_bounds__(THREADS) void chamfer_raw(
    const float* __restrict__ xyz1,
    const float* __restrict__ xyz2,
    float* __restrict__ out)
{
    int bid = blockIdx.x;
    int dir   = bid & 1;                 bid >>= 1;
    int chunk = bid & (FSPLIT - 1);      bid /= FSPLIT;
    int atile = bid & (FATILES - 1);     bid /= FATILES;
    int batch = bid;

    const float* A  = dir ? xyz2 : xyz1;
    const float* Bp = dir ? xyz1 : xyz2;
    float* o = out + (dir ? (B_ * N_) : 0);

    const int a0 = batch * N_ + atile * FAPB + threadIdx.x;

    float ax2[FP], ay2[FP], az2[FP], aw[FP], m[FP];
#pragma unroll
    for (int p = 0; p < FP; ++p) {
        int idx = a0 + p * THREADS;
        float x = A[3 * idx + 0];
        float y = A[3 * idx + 1];
        float z = A[3 * idx + 2];
        ax2[p] = -2.0f * x;
        ay2[p] = -2.0f * y;
        az2[p] = -2.0f * z;
        aw[p]  = fmaf(x, x, fmaf(y, y, z * z));
        m[p]   = FLT_MAX;
    }

    const float* bp = Bp + 3 * (batch * M_ + chunk * FCHUNK);
#pragma unroll 2
    for (int j = 0; j < FCHUNK; j += 2) {
        float b0x = bp[3 * j + 0], b0y = bp[3 * j + 1], b0z = bp[3 * j + 2];
        float b1x = bp[3 * j + 3], b1y = bp[3 * j + 4], b1z = bp[3 * j + 5];
        float b0w = fmaf(b0x, b0x, fmaf(b0y, b0y, b0z * b0z));
        float b1w = fmaf(b1x, b1x, fmaf(b1y, b1y, b1z * b1z));
#pragma unroll
        for (int p = 0; p < FP; ++p) {
            float t0 = fmaf(ax2[p], b0x, b0w);
            t0 = fmaf(ay2[p], b0y, t0);
            t0 = fmaf(az2[p], b0z, t0);
            float t1 = fmaf(ax2[p], b1x, b1w);
            t1 = fmaf(ay2[p], b1y, t1);
            t1 = fmaf(az2[p], b1z, t1);
            m[p] = fminf(m[p], fminf(t0, t1));
        }
    }

#pragma unroll
    for (int p = 0; p < FP; ++p) {
        float d = fmaxf(aw[p] + m[p], 0.0f);
        atomicMin((unsigned int*)(o + a0 + p * THREADS), __float_as_uint(d));
    }
}

extern "C" void kernel_launch(void* const* d_in, const int* in_sizes, int n_in,
                              void* d_out, int out_size, void* d_ws, size_t ws_size,
                              hipStream_t stream) {
    const float* xyz1 = (const float*)d_in[0];
    const float* xyz2 = (const float*)d_in[1];
    float* out = (float*)d_out;

    const int n_out = B_ * N_ + B_ * M_;   // 131072

    const size_t need = (size_t)(B_ * (N_ + M_)) * sizeof(float4);  // 2 MiB
    if (ws_size >= need) {
        float4* pk1 = (float4*)d_ws;          // [B*N]; pk2 follows at [B*M]
        prep_kernel<<<(n_out + 255) / 256, 256, 0, stream>>>(
            xyz1, xyz2, pk1, out, B_ * N_, n_out);
        chamfer_lds<<<NBLOCKS, THREADS, 0, stream>>>(pk1, pk1 + (size_t)B_ * N_, out);
    } else {
        init_kernel<<<(n_out + 255) / 256, 256, 0, stream>>>(out, n_out);
        chamfer_raw<<<FNBLOCKS, THREADS, 0, stream>>>(xyz1, xyz2, out);
    }
}